// Round 1
// baseline (2100.022 us; speedup 1.0000x reference)
//
#include <hip/hip_runtime.h>

#define BB 4096
#define TT 512
#define HH 10

__device__ __forceinline__ float fast_rcp(float x) { return __builtin_amdgcn_rcpf(x); }

__device__ __forceinline__ float sigm(float z) {
    return fast_rcp(1.0f + __expf(-z));
}

__device__ __forceinline__ float tanh_(float z) {
    float az = fabsf(z);
    float e = __expf(-2.0f * az);
    float r = (1.0f - e) * fast_rcp(1.0f + e);
    return copysignf(r, z);
}

__global__ __launch_bounds__(64) void lstm_fused_kernel(
    const float* __restrict__ x, const float* __restrict__ h0, const float* __restrict__ c0,
    const float* __restrict__ W_ih, const float* __restrict__ W_hh,
    const float* __restrict__ b_ih, const float* __restrict__ b_hh,
    const float* __restrict__ W1, const float* __restrict__ b1,
    const float* __restrict__ W2, const float* __restrict__ b2,
    float* __restrict__ out)
{
    // LDS weight staging (float4-aligned)
    __shared__ float4 sWhhT4[100]; // [j][q], j<10, q<10 -> gates 4q..4q+3 ; sWhhT[j*40+g] = W_hh[g][j]
    __shared__ float4 sB4[10];     // b_ih + b_hh, flat 40
    __shared__ float4 sWih4[10];   // W_ih flat 40
    __shared__ float4 sW1T4[30];   // [j][q3], 12 floats per row (10 valid + 2 zero pad)
    __shared__ float4 sB14[3];     // b1 padded to 12
    __shared__ float4 sW24[3];     // W2 padded to 12
    __shared__ float  sB2s;

    const int tid = threadIdx.x;

    {
        float* p = (float*)sWhhT4;
        for (int l = tid; l < 400; l += 64) {
            int j = l / 40, g = l % 40;
            p[l] = W_hh[g * 10 + j];
        }
        float* pb = (float*)sB4;
        float* pw = (float*)sWih4;
        if (tid < 40) { pb[tid] = b_ih[tid] + b_hh[tid]; pw[tid] = W_ih[tid]; }
        float* p1 = (float*)sW1T4;
        for (int l = tid; l < 120; l += 64) {
            int j = l / 12, k = l % 12;
            p1[l] = (k < 10) ? W1[k * 10 + j] : 0.0f;
        }
        float* pb1 = (float*)sB14;
        float* pw2 = (float*)sW24;
        if (tid < 12) {
            pb1[tid] = (tid < 10) ? b1[tid] : 0.0f;
            pw2[tid] = (tid < 10) ? W2[tid] : 0.0f;
        }
        if (tid == 0) sB2s = b2[0];
    }
    __syncthreads();

    const int b = blockIdx.x * 64 + tid;
    float h[HH], c[HH];
#pragma unroll
    for (int j = 0; j < HH; j++) {
        h[j] = h0[b * HH + j];
        c[j] = c0[b * HH + j];
    }

    const float* xb = x + (size_t)b * TT;
    float* ob = out + (size_t)b * TT;

    float4 outv;

    for (int t = 0; t < TT; t++) {
        // stop LLVM from hoisting the loop-invariant LDS weight loads (would spill)
        asm volatile("" ::: "memory");

        const float xv = xb[t];

        // ---- gates[40] = bsum + xv*W_ih + h @ W_hh^T ----
        float gs[40];
#pragma unroll
        for (int q = 0; q < 10; q++) {
            float4 bb = sB4[q];
            float4 wi = sWih4[q];
            gs[4 * q + 0] = bb.x + xv * wi.x;
            gs[4 * q + 1] = bb.y + xv * wi.y;
            gs[4 * q + 2] = bb.z + xv * wi.z;
            gs[4 * q + 3] = bb.w + xv * wi.w;
        }
#pragma unroll
        for (int j = 0; j < HH; j++) {
            const float hj = h[j];
#pragma unroll
            for (int q = 0; q < 10; q++) {
                float4 w = sWhhT4[j * 10 + q];
                gs[4 * q + 0] += hj * w.x;
                gs[4 * q + 1] += hj * w.y;
                gs[4 * q + 2] += hj * w.z;
                gs[4 * q + 3] += hj * w.w;
            }
        }

        // ---- activations + state update ----
#pragma unroll
        for (int u = 0; u < HH; u++) {
            float iv = sigm(gs[u]);
            float fv = sigm(gs[10 + u]);
            float gv = tanh_(gs[20 + u]);
            float ov = sigm(gs[30 + u]);
            float cn = fv * c[u] + iv * gv;
            c[u] = cn;
            h[u] = ov * tanh_(cn);
        }

        // ---- regressor: W2 . relu(W1 h + b1) + b2 + xv ----
        float4 r0 = sB14[0], r1 = sB14[1], r2 = sB14[2];
#pragma unroll
        for (int j = 0; j < HH; j++) {
            const float hj = h[j];
            float4 w0 = sW1T4[j * 3 + 0];
            float4 w1 = sW1T4[j * 3 + 1];
            float4 w2 = sW1T4[j * 3 + 2];
            r0.x += hj * w0.x; r0.y += hj * w0.y; r0.z += hj * w0.z; r0.w += hj * w0.w;
            r1.x += hj * w1.x; r1.y += hj * w1.y; r1.z += hj * w1.z; r1.w += hj * w1.w;
            r2.x += hj * w2.x; r2.y += hj * w2.y; r2.z += hj * w2.z; r2.w += hj * w2.w;
        }
        float4 v0 = sW24[0], v1 = sW24[1], v2 = sW24[2];
        float s = sB2s + xv;
        s += fmaxf(r0.x, 0.0f) * v0.x + fmaxf(r0.y, 0.0f) * v0.y +
             fmaxf(r0.z, 0.0f) * v0.z + fmaxf(r0.w, 0.0f) * v0.w;
        s += fmaxf(r1.x, 0.0f) * v1.x + fmaxf(r1.y, 0.0f) * v1.y +
             fmaxf(r1.z, 0.0f) * v1.z + fmaxf(r1.w, 0.0f) * v1.w;
        s += fmaxf(r2.x, 0.0f) * v2.x + fmaxf(r2.y, 0.0f) * v2.y +
             fmaxf(r2.z, 0.0f) * v2.z + fmaxf(r2.w, 0.0f) * v2.w;

        // pack 4 outputs, store as float4
        const int r = t & 3;
        if (r == 0) outv.x = s;
        else if (r == 1) outv.y = s;
        else if (r == 2) outv.z = s;
        else {
            outv.w = s;
            *(float4*)(&ob[t - 3]) = outv;
        }
    }
}

extern "C" void kernel_launch(void* const* d_in, const int* in_sizes, int n_in,
                              void* d_out, int out_size, void* d_ws, size_t ws_size,
                              hipStream_t stream) {
    const float* x    = (const float*)d_in[0];
    const float* h0   = (const float*)d_in[1];
    const float* c0   = (const float*)d_in[2];
    const float* W_ih = (const float*)d_in[3];
    const float* W_hh = (const float*)d_in[4];
    const float* b_ih = (const float*)d_in[5];
    const float* b_hh = (const float*)d_in[6];
    const float* W1   = (const float*)d_in[7];
    const float* b1   = (const float*)d_in[8];
    const float* W2   = (const float*)d_in[9];
    const float* b2   = (const float*)d_in[10];
    float* out = (float*)d_out;

    dim3 grid(BB / 64);
    dim3 block(64);
    lstm_fused_kernel<<<grid, block, 0, stream>>>(x, h0, c0, W_ih, W_hh, b_ih, b_hh,
                                                  W1, b1, W2, b2, out);
}

// Round 2
// 368.523 us; speedup vs baseline: 5.6985x; 5.6985x over previous
//
#include <hip/hip_runtime.h>

#define BB 4096
#define TT 512
#define HH 10

__device__ __forceinline__ float fast_rcp(float x) { return __builtin_amdgcn_rcpf(x); }
__device__ __forceinline__ float sigm(float z) { return fast_rcp(1.0f + __expf(-z)); }
// tanh(z) = 2*sigmoid(2z) - 1
__device__ __forceinline__ float tanh_(float z) { return 2.0f * sigm(2.0f * z) - 1.0f; }

// 4 lanes per batch element. Lane q (within quad) owns hidden units u = q + 4k, k=0..2
// (valid while u < 10, so ownership is 3/3/2/2). All weights for the owned units live
// in registers; h is exchanged across the quad with bpermute shuffles each step.
__global__ __launch_bounds__(64, 1) void lstm_quad_kernel(
    const float* __restrict__ x, const float* __restrict__ h0, const float* __restrict__ c0,
    const float* __restrict__ W_ih, const float* __restrict__ W_hh,
    const float* __restrict__ b_ih, const float* __restrict__ b_hh,
    const float* __restrict__ W1, const float* __restrict__ b1,
    const float* __restrict__ W2, const float* __restrict__ b2,
    float* __restrict__ out)
{
    const int lane = threadIdx.x;         // block = 64 = one wave
    const int q = lane & 3;
    const int e = (blockIdx.x * 64 + lane) >> 2;   // batch element, 16 per wave

    // ---- per-lane register weights ----
    float W[3][4][10];      // [k][gate][j]  (gate order i,f,g,o)
    float wih[3][4], bsum[3][4];
    float W1r[3][10], b1r[3], W2r[3];

#pragma unroll
    for (int k = 0; k < 3; k++) {
        const int u = q + 4 * k;
        const bool valid = (u < HH);
        const float m = valid ? 1.0f : 0.0f;
        const int uu = valid ? u : 0;
#pragma unroll
        for (int g = 0; g < 4; g++) {
            const int row = g * HH + uu;
            const float2* rp = (const float2*)(W_hh + row * HH);  // row*10 floats -> 8B aligned
#pragma unroll
            for (int jj = 0; jj < 5; jj++) {
                float2 w = rp[jj];
                W[k][g][2 * jj]     = w.x * m;
                W[k][g][2 * jj + 1] = w.y * m;
            }
            wih[k][g]  = W_ih[row] * m;
            bsum[k][g] = (b_ih[row] + b_hh[row]) * m;
        }
        const float2* r1 = (const float2*)(W1 + uu * HH);
#pragma unroll
        for (int jj = 0; jj < 5; jj++) {
            float2 w = r1[jj];
            W1r[k][2 * jj]     = w.x * m;
            W1r[k][2 * jj + 1] = w.y * m;
        }
        b1r[k] = b1[uu] * m;
        W2r[k] = W2[uu] * m;
    }
    const float b2s = b2[0];

    // ---- state ----
    float h[10], c[3];
#pragma unroll
    for (int j = 0; j < 10; j++) h[j] = h0[e * HH + j];
#pragma unroll
    for (int k = 0; k < 3; k++) {
        const int u = q + 4 * k;
        c[k] = (u < HH) ? c0[e * HH + u] : 0.0f;
    }

    const float4* xq  = (const float4*)(x + (size_t)e * TT);
    float4*       ob4 = (float4*)(out + (size_t)e * TT);
    const int quadbase = lane & ~3;

    float4 xc = xq[0];
    for (int gb = 0; gb < TT / 4; gb++) {
        // prefetch next 4 x values (uniform within quad; latency hidden under 4 steps)
        float4 xn = xq[(gb + 1 < TT / 4) ? gb + 1 : gb];
        float4 outv;

#pragma unroll
        for (int r = 0; r < 4; r++) {
            const float xv = (r == 0) ? xc.x : (r == 1) ? xc.y : (r == 2) ? xc.z : xc.w;

            // ---- own gates + state update ----
            float hn[3];
#pragma unroll
            for (int k = 0; k < 3; k++) {
                float g0 = bsum[k][0] + xv * wih[k][0];
                float g1 = bsum[k][1] + xv * wih[k][1];
                float g2 = bsum[k][2] + xv * wih[k][2];
                float g3 = bsum[k][3] + xv * wih[k][3];
#pragma unroll
                for (int j = 0; j < 10; j++) {
                    const float hj = h[j];
                    g0 += hj * W[k][0][j];
                    g1 += hj * W[k][1][j];
                    g2 += hj * W[k][2][j];
                    g3 += hj * W[k][3][j];
                }
                const float iv = sigm(g0);
                const float fv = sigm(g1);
                const float gv = tanh_(g2);
                const float ov = sigm(g3);
                const float cn = fv * c[k] + iv * gv;
                c[k] = cn;
                hn[k] = ov * tanh_(cn);
            }

            // ---- broadcast h across the quad (10 bpermutes, one latency hop) ----
#pragma unroll
            for (int k = 0; k < 3; k++) {
#pragma unroll
                for (int qq = 0; qq < 4; qq++) {
                    const int u = qq + 4 * k;
                    if (u < HH) h[u] = __shfl(hn[k], quadbase | qq, 64);
                }
            }

            // ---- regressor partial: relu(W1 h + b1) . W2 over owned units ----
            float sp = 0.0f;
#pragma unroll
            for (int k = 0; k < 3; k++) {
                float acc = b1r[k];
#pragma unroll
                for (int j = 0; j < 10; j++) acc += h[j] * W1r[k][j];
                sp += fmaxf(acc, 0.0f) * W2r[k];
            }
            sp += __shfl_xor(sp, 1);
            sp += __shfl_xor(sp, 2);
            const float s = sp + b2s + xv;

            if (r == 0) outv.x = s;
            else if (r == 1) outv.y = s;
            else if (r == 2) outv.z = s;
            else outv.w = s;
        }

        if (q == 0) ob4[gb] = outv;
        xc = xn;
    }
}

extern "C" void kernel_launch(void* const* d_in, const int* in_sizes, int n_in,
                              void* d_out, int out_size, void* d_ws, size_t ws_size,
                              hipStream_t stream) {
    const float* x    = (const float*)d_in[0];
    const float* h0   = (const float*)d_in[1];
    const float* c0   = (const float*)d_in[2];
    const float* W_ih = (const float*)d_in[3];
    const float* W_hh = (const float*)d_in[4];
    const float* b_ih = (const float*)d_in[5];
    const float* b_hh = (const float*)d_in[6];
    const float* W1   = (const float*)d_in[7];
    const float* b1   = (const float*)d_in[8];
    const float* W2   = (const float*)d_in[9];
    const float* b2   = (const float*)d_in[10];
    float* out = (float*)d_out;

    dim3 grid(BB * 4 / 64);   // 256 blocks: one wave per CU
    dim3 block(64);
    lstm_quad_kernel<<<grid, block, 0, stream>>>(x, h0, c0, W_ih, W_hh, b_ih, b_hh,
                                                 W1, b1, W2, b2, out);
}

// Round 3
// 283.159 us; speedup vs baseline: 7.4164x; 1.3015x over previous
//
#include <hip/hip_runtime.h>

#define BB 4096
#define TT 512
#define HH 10

__device__ __forceinline__ float fast_rcp(float x) { return __builtin_amdgcn_rcpf(x); }
__device__ __forceinline__ float sigm(float z) { return fast_rcp(1.0f + __expf(-z)); }
// tanh(z) = 2*sigmoid(2z) - 1
__device__ __forceinline__ float tanh_(float z) { return 2.0f * sigm(2.0f * z) - 1.0f; }

// DPP quad_perm: CTRL = q0 | q1<<2 | q2<<4 | q3<<6. VALU-pipe cross-lane, ~4cy latency.
template <int CTRL>
__device__ __forceinline__ float dpp_qperm(float v) {
    return __int_as_float(__builtin_amdgcn_update_dpp(
        0, __float_as_int(v), CTRL, 0xf, 0xf, true));
}
// broadcast lane q of each quad to all 4: ctrl = q*0x55
#define BCAST0 0x00
#define BCAST1 0x55
#define BCAST2 0xAA
#define BCAST3 0xFF
#define XOR1   0xB1  // [1,0,3,2]
#define XOR2   0x4E  // [2,3,0,1]

// 4 lanes per batch element. Lane q owns hidden units u = q + 4k (3/3/2/2).
// All weights in registers; h exchanged across the quad with DPP quad_perm.
__global__ __launch_bounds__(64, 1) void lstm_quad_dpp_kernel(
    const float* __restrict__ x, const float* __restrict__ h0, const float* __restrict__ c0,
    const float* __restrict__ W_ih, const float* __restrict__ W_hh,
    const float* __restrict__ b_ih, const float* __restrict__ b_hh,
    const float* __restrict__ W1, const float* __restrict__ b1,
    const float* __restrict__ W2, const float* __restrict__ b2,
    float* __restrict__ out)
{
    const int lane = threadIdx.x;                  // block = 64 = one wave
    const int q = lane & 3;
    const int e = (blockIdx.x * 64 + lane) >> 2;   // batch element, 16 per wave

    // ---- per-lane register weights ----
    float W[3][4][10];      // [k][gate][j]  (gate order i,f,g,o)
    float wih[3][4], bsum[3][4];
    float W1r[3][10], b1r[3], W2r[3];

#pragma unroll
    for (int k = 0; k < 3; k++) {
        const int u = q + 4 * k;
        const bool valid = (u < HH);
        const float m = valid ? 1.0f : 0.0f;
        const int uu = valid ? u : 0;
#pragma unroll
        for (int g = 0; g < 4; g++) {
            const int row = g * HH + uu;
            const float2* rp = (const float2*)(W_hh + row * HH);
#pragma unroll
            for (int jj = 0; jj < 5; jj++) {
                float2 w = rp[jj];
                W[k][g][2 * jj]     = w.x * m;
                W[k][g][2 * jj + 1] = w.y * m;
            }
            wih[k][g]  = W_ih[row] * m;
            bsum[k][g] = (b_ih[row] + b_hh[row]) * m;
        }
        const float2* r1 = (const float2*)(W1 + uu * HH);
#pragma unroll
        for (int jj = 0; jj < 5; jj++) {
            float2 w = r1[jj];
            W1r[k][2 * jj]     = w.x * m;
            W1r[k][2 * jj + 1] = w.y * m;
        }
        b1r[k] = b1[uu] * m;
        W2r[k] = W2[uu] * m;
    }
    const float b2s = b2[0];

    // ---- state ----
    float h[10], c[3];
#pragma unroll
    for (int j = 0; j < 10; j++) h[j] = h0[e * HH + j];
#pragma unroll
    for (int k = 0; k < 3; k++) {
        const int u = q + 4 * k;
        c[k] = (u < HH) ? c0[e * HH + u] : 0.0f;
    }

    const float4* xq  = (const float4*)(x + (size_t)e * TT);
    float4*       ob4 = (float4*)(out + (size_t)e * TT);

    float4 xc = xq[0];
    for (int gb = 0; gb < TT / 4; gb++) {
        float4 xn = xq[(gb + 1 < TT / 4) ? gb + 1 : gb];
        float4 outv;

#pragma unroll
        for (int r = 0; r < 4; r++) {
            const float xv = (r == 0) ? xc.x : (r == 1) ? xc.y : (r == 2) ? xc.z : xc.w;

            // ---- own gates + state update ----
            float hn[3];
#pragma unroll
            for (int k = 0; k < 3; k++) {
                float g0 = fmaf(xv, wih[k][0], bsum[k][0]);
                float g1 = fmaf(xv, wih[k][1], bsum[k][1]);
                float g2 = fmaf(xv, wih[k][2], bsum[k][2]);
                float g3 = fmaf(xv, wih[k][3], bsum[k][3]);
#pragma unroll
                for (int j = 0; j < 10; j++) {
                    const float hj = h[j];
                    g0 = fmaf(hj, W[k][0][j], g0);
                    g1 = fmaf(hj, W[k][1][j], g1);
                    g2 = fmaf(hj, W[k][2][j], g2);
                    g3 = fmaf(hj, W[k][3][j], g3);
                }
                const float iv = sigm(g0);
                const float fv = sigm(g1);
                const float gv = tanh_(g2);
                const float ov = sigm(g3);
                const float cn = fmaf(fv, c[k], iv * gv);
                c[k] = cn;
                hn[k] = ov * tanh_(cn);
            }

            // ---- broadcast h across the quad: DPP quad_perm (VALU pipe, no LDS) ----
            h[0] = dpp_qperm<BCAST0>(hn[0]);
            h[1] = dpp_qperm<BCAST1>(hn[0]);
            h[2] = dpp_qperm<BCAST2>(hn[0]);
            h[3] = dpp_qperm<BCAST3>(hn[0]);
            h[4] = dpp_qperm<BCAST0>(hn[1]);
            h[5] = dpp_qperm<BCAST1>(hn[1]);
            h[6] = dpp_qperm<BCAST2>(hn[1]);
            h[7] = dpp_qperm<BCAST3>(hn[1]);
            h[8] = dpp_qperm<BCAST0>(hn[2]);
            h[9] = dpp_qperm<BCAST1>(hn[2]);

            // ---- regressor partial: relu(W1 h + b1) . W2 over owned units ----
            float sp = 0.0f;
#pragma unroll
            for (int k = 0; k < 3; k++) {
                float acc = b1r[k];
#pragma unroll
                for (int j = 0; j < 10; j++) acc = fmaf(h[j], W1r[k][j], acc);
                sp = fmaf(fmaxf(acc, 0.0f), W2r[k], sp);
            }
            // quad reduction on the VALU pipe
            sp += dpp_qperm<XOR1>(sp);
            sp += dpp_qperm<XOR2>(sp);
            const float s = sp + b2s + xv;

            if (r == 0) outv.x = s;
            else if (r == 1) outv.y = s;
            else if (r == 2) outv.z = s;
            else outv.w = s;
        }

        if (q == 0) ob4[gb] = outv;
        xc = xn;
    }
}

extern "C" void kernel_launch(void* const* d_in, const int* in_sizes, int n_in,
                              void* d_out, int out_size, void* d_ws, size_t ws_size,
                              hipStream_t stream) {
    const float* x    = (const float*)d_in[0];
    const float* h0   = (const float*)d_in[1];
    const float* c0   = (const float*)d_in[2];
    const float* W_ih = (const float*)d_in[3];
    const float* W_hh = (const float*)d_in[4];
    const float* b_ih = (const float*)d_in[5];
    const float* b_hh = (const float*)d_in[6];
    const float* W1   = (const float*)d_in[7];
    const float* b1   = (const float*)d_in[8];
    const float* W2   = (const float*)d_in[9];
    const float* b2   = (const float*)d_in[10];
    float* out = (float*)d_out;

    dim3 grid(BB * 4 / 64);   // 256 blocks: one wave per CU
    dim3 block(64);
    lstm_quad_dpp_kernel<<<grid, block, 0, stream>>>(x, h0, c0, W_ih, W_hh, b_ih, b_hh,
                                                     W1, b1, W2, b2, out);
}

// Round 4
// 281.042 us; speedup vs baseline: 7.4723x; 1.0075x over previous
//
#include <hip/hip_runtime.h>

#define BB 4096
#define TT 512
#define HH 10

__device__ __forceinline__ float fast_rcp(float x) { return __builtin_amdgcn_rcpf(x); }
__device__ __forceinline__ float sigm(float z) { return fast_rcp(1.0f + __expf(-z)); }
// tanh(z) = 2*sigmoid(2z) - 1
__device__ __forceinline__ float tanh_(float z) { return 2.0f * sigm(2.0f * z) - 1.0f; }

// DPP quad_perm: CTRL = q0 | q1<<2 | q2<<4 | q3<<6. VALU-pipe cross-lane, ~4cy latency.
template <int CTRL>
__device__ __forceinline__ float dpp_qperm(float v) {
    return __int_as_float(__builtin_amdgcn_update_dpp(
        0, __float_as_int(v), CTRL, 0xf, 0xf, true));
}
#define BCAST0 0x00
#define BCAST1 0x55
#define BCAST2 0xAA
#define BCAST3 0xFF
#define XOR1   0xB1  // [1,0,3,2]
#define XOR2   0x4E  // [2,3,0,1]

// 4 lanes per batch element. Lane q owns hidden units u = q + 4k (3/3/2/2).
// All weights in registers (amdgpu_waves_per_eu(1,1) unlocks the 512-VGPR budget;
// we run exactly 1 wave per CU so occupancy=1/EU is free); h exchanged via DPP.
__global__ __launch_bounds__(64)
__attribute__((amdgpu_waves_per_eu(1, 1)))
void lstm_quad_dpp_kernel(
    const float* __restrict__ x, const float* __restrict__ h0, const float* __restrict__ c0,
    const float* __restrict__ W_ih, const float* __restrict__ W_hh,
    const float* __restrict__ b_ih, const float* __restrict__ b_hh,
    const float* __restrict__ W1, const float* __restrict__ b1,
    const float* __restrict__ W2, const float* __restrict__ b2,
    float* __restrict__ out)
{
    const int lane = threadIdx.x;                  // block = 64 = one wave
    const int q = lane & 3;
    const int e = (blockIdx.x * 64 + lane) >> 2;   // batch element, 16 per wave

    // ---- per-lane register weights ----
    float W[3][4][10];      // [k][gate][j]  (gate order i,f,g,o)
    float wih[3][4], bsum[3][4];
    float W1r[3][10], b1r[3], W2r[3];

#pragma unroll
    for (int k = 0; k < 3; k++) {
        const int u = q + 4 * k;
        const bool valid = (u < HH);
        const float m = valid ? 1.0f : 0.0f;
        const int uu = valid ? u : 0;
#pragma unroll
        for (int g = 0; g < 4; g++) {
            const int row = g * HH + uu;
            const float2* rp = (const float2*)(W_hh + row * HH);
#pragma unroll
            for (int jj = 0; jj < 5; jj++) {
                float2 w = rp[jj];
                W[k][g][2 * jj]     = w.x * m;
                W[k][g][2 * jj + 1] = w.y * m;
            }
            wih[k][g]  = W_ih[row] * m;
            bsum[k][g] = (b_ih[row] + b_hh[row]) * m;
        }
        const float2* r1 = (const float2*)(W1 + uu * HH);
#pragma unroll
        for (int jj = 0; jj < 5; jj++) {
            float2 w = r1[jj];
            W1r[k][2 * jj]     = w.x * m;
            W1r[k][2 * jj + 1] = w.y * m;
        }
        b1r[k] = b1[uu] * m;
        W2r[k] = W2[uu] * m;
    }
    const float b2s = b2[0];

    // ---- state ----
    float h[10], c[3];
#pragma unroll
    for (int j = 0; j < 10; j++) h[j] = h0[e * HH + j];
#pragma unroll
    for (int k = 0; k < 3; k++) {
        const int u = q + 4 * k;
        c[k] = (u < HH) ? c0[e * HH + u] : 0.0f;
    }

    const float4* xq  = (const float4*)(x + (size_t)e * TT);
    float4*       ob4 = (float4*)(out + (size_t)e * TT);

    float4 xc = xq[0];
    for (int gb = 0; gb < TT / 4; gb++) {
        float4 xn = xq[(gb + 1 < TT / 4) ? gb + 1 : gb];
        float4 outv;

#pragma unroll
        for (int r = 0; r < 4; r++) {
            const float xv = (r == 0) ? xc.x : (r == 1) ? xc.y : (r == 2) ? xc.z : xc.w;

            // ---- own gates + state update ----
            float hn[3];
#pragma unroll
            for (int k = 0; k < 3; k++) {
                float g0 = fmaf(xv, wih[k][0], bsum[k][0]);
                float g1 = fmaf(xv, wih[k][1], bsum[k][1]);
                float g2 = fmaf(xv, wih[k][2], bsum[k][2]);
                float g3 = fmaf(xv, wih[k][3], bsum[k][3]);
#pragma unroll
                for (int j = 0; j < 10; j++) {
                    const float hj = h[j];
                    g0 = fmaf(hj, W[k][0][j], g0);
                    g1 = fmaf(hj, W[k][1][j], g1);
                    g2 = fmaf(hj, W[k][2][j], g2);
                    g3 = fmaf(hj, W[k][3][j], g3);
                }
                const float iv = sigm(g0);
                const float fv = sigm(g1);
                const float gv = tanh_(g2);
                const float ov = sigm(g3);
                const float cn = fmaf(fv, c[k], iv * gv);
                c[k] = cn;
                hn[k] = ov * tanh_(cn);
            }

            // ---- broadcast h across the quad: DPP quad_perm (VALU pipe, no LDS) ----
            h[0] = dpp_qperm<BCAST0>(hn[0]);
            h[1] = dpp_qperm<BCAST1>(hn[0]);
            h[2] = dpp_qperm<BCAST2>(hn[0]);
            h[3] = dpp_qperm<BCAST3>(hn[0]);
            h[4] = dpp_qperm<BCAST0>(hn[1]);
            h[5] = dpp_qperm<BCAST1>(hn[1]);
            h[6] = dpp_qperm<BCAST2>(hn[1]);
            h[7] = dpp_qperm<BCAST3>(hn[1]);
            h[8] = dpp_qperm<BCAST0>(hn[2]);
            h[9] = dpp_qperm<BCAST1>(hn[2]);

            // ---- regressor partial: relu(W1 h + b1) . W2 over owned units ----
            float sp = 0.0f;
#pragma unroll
            for (int k = 0; k < 3; k++) {
                float acc = b1r[k];
#pragma unroll
                for (int j = 0; j < 10; j++) acc = fmaf(h[j], W1r[k][j], acc);
                sp = fmaf(fmaxf(acc, 0.0f), W2r[k], sp);
            }
            // quad reduction on the VALU pipe
            sp += dpp_qperm<XOR1>(sp);
            sp += dpp_qperm<XOR2>(sp);
            const float s = sp + b2s + xv;

            if (r == 0) outv.x = s;
            else if (r == 1) outv.y = s;
            else if (r == 2) outv.z = s;
            else outv.w = s;
        }

        if (q == 0) ob4[gb] = outv;
        xc = xn;
    }
}

extern "C" void kernel_launch(void* const* d_in, const int* in_sizes, int n_in,
                              void* d_out, int out_size, void* d_ws, size_t ws_size,
                              hipStream_t stream) {
    const float* x    = (const float*)d_in[0];
    const float* h0   = (const float*)d_in[1];
    const float* c0   = (const float*)d_in[2];
    const float* W_ih = (const float*)d_in[3];
    const float* W_hh = (const float*)d_in[4];
    const float* b_ih = (const float*)d_in[5];
    const float* b_hh = (const float*)d_in[6];
    const float* W1   = (const float*)d_in[7];
    const float* b1   = (const float*)d_in[8];
    const float* W2   = (const float*)d_in[9];
    const float* b2   = (const float*)d_in[10];
    float* out = (float*)d_out;

    dim3 grid(BB * 4 / 64);   // 256 blocks: one wave per CU
    dim3 block(64);
    lstm_quad_dpp_kernel<<<grid, block, 0, stream>>>(x, h0, c0, W_ih, W_hh, b_ih, b_hh,
                                                     W1, b1, W2, b2, out);
}